// Round 1
// 58.966 us; speedup vs baseline: 1.0026x; 1.0026x over previous
//
#include <hip/hip_runtime.h>
#include <math.h>

// QuantumDecoder: the reference's 2^14-dim state-vector simulation collapses
// analytically:
//   - RX layer  -> product state, P(bit_w=1) = sin^2(latent_w/2), bits independent
//   - CNOT chain -> basis permutation: bit_i -> XOR(b_0..b_i)
//   - RZ layer  -> pure phase, cancels in |amp|^2  => `weights` input is UNUSED
//   => <Z_i> = prod_{w<=i} cos(latent[b,w])   (prefix product of cosines)
// Then out = z @ W_map^T + b_map.  Total ~2.2 MFLOP: launch-latency bound.
//
// R1: replace {barrier, serial 14-chain on lane 0, barrier} with a 4-step
// __shfl_up prefix product in wave 0 + a single barrier. Purpose: falsify or
// confirm the "fixed harness overhead dominates" theory — kernel intrinsic
// cost is ~2-5 us vs 59 us measured; top rocprof dispatches are 256 MiB
// harness fills at 85% HBM peak (39.4 us each), outside kernel control.

constexpr int LATENT = 14;
constexpr int OUT    = 784;
constexpr int BATCH  = 128;

__global__ __launch_bounds__(256)
void qdec_kernel(const float* __restrict__ latent,   // [BATCH, LATENT]
                 const float* __restrict__ W_map,    // [OUT, LATENT]
                 const float* __restrict__ b_map,    // [OUT]
                 float* __restrict__ out)            // [BATCH, OUT]
{
    __shared__ float z[LATENT];

    const int b = blockIdx.y;
    const int t = threadIdx.x;

    // Wave 0 only: lanes 0..13 compute cos(latent), then an inclusive prefix
    // product via log2 shuffle steps (d = 1,2,4,8 covers 14 lanes). Lanes
    // 14..63 carry neutral 1.0f and are never stored. Single barrier total.
    if (t < 64) {
        float c = 1.0f;
        if (t < LATENT) c = cosf(latent[b * LATENT + t]);
        float p = c;
        #pragma unroll
        for (int d = 1; d < 16; d <<= 1) {
            float u = __shfl_up(p, d, 64);
            if (t >= d) p *= u;
        }
        if (t < LATENT) z[t] = p;
    }
    __syncthreads();

    const int o = blockIdx.x * blockDim.x + t;
    if (o < OUT) {
        float acc = b_map[o];
        const float* wrow = W_map + o * LATENT;   // 56 B row; L1/L2 resident (44 KB total)
        #pragma unroll
        for (int i = 0; i < LATENT; ++i) {
            acc = fmaf(z[i], wrow[i], acc);
        }
        out[b * OUT + o] = acc;
    }
}

extern "C" void kernel_launch(void* const* d_in, const int* in_sizes, int n_in,
                              void* d_out, int out_size, void* d_ws, size_t ws_size,
                              hipStream_t stream)
{
    const float* latent = (const float*)d_in[0];   // [128, 14]
    // d_in[1] = weights [14,14] — provably unused (RZ phases cancel in |.|^2)
    const float* W_map  = (const float*)d_in[2];   // [784, 14]
    const float* b_map  = (const float*)d_in[3];   // [784]
    float*       out    = (float*)d_out;           // [128, 784] fp32

    dim3 grid((OUT + 255) / 256, BATCH);
    qdec_kernel<<<grid, 256, 0, stream>>>(latent, W_map, b_map, out);
}